// Round 15
// baseline (483.943 us; speedup 1.0000x reference)
//
#include <hip/hip_runtime.h>
#include <math.h>

#define E_      200
#define EP      224      // K padded to 7*32
#define NL      28415
#define NLP     28416
#define L0      256
#define MROWS   5120     // 20*256
#define CORN    1000
#define NEDGE   454640
#define LOG2E   1.44269504088896f
#define LN2     0.69314718055994531f
#define PREP_TOT 36352   // NLP + 512 + 2304 + MROWS
#define SLAB    (MROWS*32)   // k-major slab stride (elements)
#define NHALF   14208        // NLP/2

typedef unsigned short u16;
typedef __attribute__((ext_vector_type(8))) short s16x8;
typedef __attribute__((ext_vector_type(4))) float f32x4;

__device__ __forceinline__ u16 f2b(float f){
    unsigned u = __float_as_uint(f);
    unsigned r = (u + 0x7fffu + ((u >> 16) & 1u)) >> 16;
    return (u16)r;
}
__device__ __forceinline__ float b2f(u16 h){ return __uint_as_float(((unsigned)h) << 16); }

__device__ __forceinline__ float fexp2(float x){
    float r; asm("v_exp_f32 %0, %1" : "=v"(r) : "v"(x)); return r;
}

// ---------------- fused prep kernel (+ degree count) ----------------

struct PrepArgs {
    const float* g;   u16* gbf;
    const float* gw1; u16* wdn1;
    const float* gw2; u16* wdn2;
    const float* cw1; u16* wcv1;
    const float* cw2; u16* wcv2;
    const float* cw3; u16* wcv3;
    const int* t0; const int* t1; const int* t2; const int* t3; const int* t4;
    const float* emb; u16* xA;
};

__global__ void k_prep_all(PrepArgs a, const int* __restrict__ dste, int* __restrict__ deg){
    int bid = blockIdx.x;
    int t = threadIdx.x;
    if (bid >= PREP_TOT){           // degree-count blocks
        int e = (bid - PREP_TOT)*256 + t;
        if (e < NEDGE) atomicAdd(&deg[dste[e]], 1);
        return;
    }
    int e = t;
    if (e >= EP) return;
    if (bid < NLP){
        int n = bid;
        float v = (n < NL && e < E_) ? a.g[(size_t)n*E_ + e] : 0.f;
        a.gbf[(size_t)n*EP + e] = f2b(v);
        return;
    }
    bid -= NLP;
    if (bid < 512){
        const float* w = (bid < 256) ? a.gw1 : a.gw2;
        u16* out = (bid < 256) ? a.wdn1 : a.wdn2;
        int o = bid & 255;
        float v = (o < E_ && e < E_) ? w[(size_t)o*E_ + e] : 0.f;
        out[(size_t)o*EP + e] = f2b(v);
        return;
    }
    bid -= 512;
    if (bid < 2304){
        int which = bid / 768;
        const float* w = (which==0) ? a.cw1 : (which==1) ? a.cw2 : a.cw3;
        u16* out = (which==0) ? a.wcv1 : (which==1) ? a.wcv2 : a.wcv3;
        int r = bid - which*768;
        int kk = r >> 8, o = r & 255;
        float v = (o < E_ && e < E_) ? w[((size_t)o*E_ + e)*3 + kk] : 0.f;
        out[(size_t)r*EP + e] = f2b(v);
        return;
    }
    bid -= 2304;
    {   // embed
        int chunk = bid >> 8, l = bid & 255, s = chunk >> 2, b = chunk & 3;
        const int* tp = (s==0)?a.t0:(s==1)?a.t1:(s==2)?a.t2:(s==3)?a.t3:a.t4;
        int tok = tp[b*L0 + l];
        float v = (e < E_) ? a.emb[(size_t)tok*E_ + e] : 0.f;
        a.xA[(size_t)bid*EP + e] = f2b(v);
    }
}

// ---------------- CSR build ----------------
// single-block exclusive scan: 1024 threads x 28-element serial chunks,
// LDS scan of 1024 partials, two-pass per-thread prefix (no local array).

__global__ void k_scan(const int* __restrict__ deg, int* __restrict__ rowptr,
                       int* __restrict__ cursor){
    __shared__ int ps[1024];
    int t = threadIdx.x;
    int base = t*28;
    int s = 0;
    for (int k = 0; k < 28; ++k){
        int idx = base + k;
        s += (idx < NLP) ? deg[idx] : 0;
    }
    ps[t] = s;
    __syncthreads();
    for (int o = 1; o < 1024; o <<= 1){
        int x = (t >= o) ? ps[t-o] : 0;
        __syncthreads();
        ps[t] += x;
        __syncthreads();
    }
    int run = ps[t] - s;
    for (int k = 0; k < 28; ++k){
        int idx = base + k;
        if (idx < NLP){
            rowptr[idx] = run;
            cursor[idx] = run;
            run += deg[idx];
        }
    }
    if (t == 1023) rowptr[NLP] = ps[1023];
}

__global__ void k_scatter(const int* __restrict__ src, const int* __restrict__ dst,
                          int* __restrict__ cursor, int* __restrict__ esrc){
    int e = blockIdx.x*256 + threadIdx.x;
    if (e < NEDGE){
        int p = atomicAdd(&cursor[dst[e]], 1);
        esrc[p] = src[e];
    }
}

// half-wave (32 lanes, 28 active) per node; 8-edge unroll (8 loads in flight)
__global__ void k_agg(const u16* __restrict__ feat, const int* __restrict__ rp,
                      const int* __restrict__ esrc, u16* __restrict__ out){
    int half = threadIdx.x >> 5;
    int ln   = threadIdx.x & 31;
    int n = blockIdx.x*8 + half;
    if (n >= NL || ln >= 28) return;
    int beg = rp[n], end = rp[n+1];
    float acc0[8] = {0,0,0,0,0,0,0,0};
    float acc1[8] = {0,0,0,0,0,0,0,0};
    int i = beg;
    for (; i + 7 < end; i += 8){
        int s0 = esrc[i],   s1 = esrc[i+1], s2 = esrc[i+2], s3 = esrc[i+3];
        int s4 = esrc[i+4], s5 = esrc[i+5], s6 = esrc[i+6], s7 = esrc[i+7];
        s16x8 v0 = *(const s16x8*)(feat + (size_t)s0*EP + ln*8);
        s16x8 v1 = *(const s16x8*)(feat + (size_t)s1*EP + ln*8);
        s16x8 v2 = *(const s16x8*)(feat + (size_t)s2*EP + ln*8);
        s16x8 v3 = *(const s16x8*)(feat + (size_t)s3*EP + ln*8);
        s16x8 v4 = *(const s16x8*)(feat + (size_t)s4*EP + ln*8);
        s16x8 v5 = *(const s16x8*)(feat + (size_t)s5*EP + ln*8);
        s16x8 v6 = *(const s16x8*)(feat + (size_t)s6*EP + ln*8);
        s16x8 v7 = *(const s16x8*)(feat + (size_t)s7*EP + ln*8);
#pragma unroll
        for (int j = 0; j < 8; ++j){
            acc0[j] += (b2f((u16)v0[j]) + b2f((u16)v2[j])) + (b2f((u16)v4[j]) + b2f((u16)v6[j]));
            acc1[j] += (b2f((u16)v1[j]) + b2f((u16)v3[j])) + (b2f((u16)v5[j]) + b2f((u16)v7[j]));
        }
    }
    for (; i + 1 < end; i += 2){
        int s0 = esrc[i], s1 = esrc[i+1];
        s16x8 v0 = *(const s16x8*)(feat + (size_t)s0*EP + ln*8);
        s16x8 v1 = *(const s16x8*)(feat + (size_t)s1*EP + ln*8);
#pragma unroll
        for (int j = 0; j < 8; ++j){
            acc0[j] += b2f((u16)v0[j]);
            acc1[j] += b2f((u16)v1[j]);
        }
    }
    if (i < end){
        int s0 = esrc[i];
        s16x8 v0 = *(const s16x8*)(feat + (size_t)s0*EP + ln*8);
#pragma unroll
        for (int j = 0; j < 8; ++j) acc0[j] += b2f((u16)v0[j]);
    }
    s16x8 o;
#pragma unroll
    for (int j = 0; j < 8; ++j) o[j] = (short)f2b(acc0[j] + acc1[j]);
    *(s16x8*)(out + (size_t)n*EP + ln*8) = o;
}

// ---------------- MFMA GEMM body (modes 0/1/2) ----------------
// TRANSP=1 (mode 0 only): write output in k-major slabs [7][MROWS][32]
// MODE 2: residual add reads bf16 gbf (padded zeros) -> branchless

template<int MODE, int BM, int BN, int TRANSP>
__device__ __forceinline__ void gemm_body(char* smem, int bx, int by,
            const u16* __restrict__ A, const u16* __restrict__ B,
            u16* __restrict__ Obf, const float* __restrict__ bias,
            const u16* __restrict__ gadd16, int dil)
{
    constexpr int NSTEPS = (MODE == 0) ? 21 : 7;
    constexpr int QA = (BM*4)/256, QB = (BN*4)/256, I = BM/64, J = BN/16, WR = BM/4;
    typedef u16 (*AlT)[BM][40];
    typedef u16 (*BlT)[BN][40];
    AlT Al = (AlT)smem;
    BlT Bl = (BlT)(smem + (size_t)2*BM*40*2);

    const int tid  = threadIdx.x;
    const int lane = tid & 63;
    const int w    = tid >> 6;
    const int fr   = lane & 15;
    const int kfo  = (lane >> 4) * 8;
    const int n0     = bx * BN;
    const int m_base = by * BM;

    int ar[QA], ao[QA], brr[QB], bro[QB];
#pragma unroll
    for (int q = 0; q < QA; ++q){ int idx = q*256 + tid; ar[q] = idx >> 2; ao[q] = (idx & 3)*8; }
#pragma unroll
    for (int q = 0; q < QB; ++q){ int idx = q*256 + tid; brr[q] = idx >> 2; bro[q] = (idx & 3)*8; }

    auto aRow = [&](int row, int st)->int {
        if constexpr (MODE == 0){
            int off = (m_base & 255) + row + (st/7)*dil;
            if (off > 255) off = 255;
            return (m_base & ~255) + off;
        } else return m_base + row;
    };
    auto aCol = [&](int st)->int {
        if constexpr (MODE == 0) return (st % 7) * 32; else return st * 32;
    };
    auto bRow = [&](int row, int st)->int {
        if constexpr (MODE == 0) return (st/7)*256 + n0 + row; else return n0 + row;
    };

#pragma unroll
    for (int q = 0; q < QA; ++q){
        s16x8 v = *(const s16x8*)(A + (size_t)aRow(ar[q],0)*EP + aCol(0) + ao[q]);
        *(s16x8*)&Al[0][ar[q]][ao[q]] = v;
    }
#pragma unroll
    for (int q = 0; q < QB; ++q){
        s16x8 v = *(const s16x8*)(B + (size_t)bRow(brr[q],0)*EP + aCol(0) + bro[q]);
        *(s16x8*)&Bl[0][brr[q]][bro[q]] = v;
    }
    __syncthreads();

    f32x4 acc[I][J];
#pragma unroll
    for (int i = 0; i < I; ++i)
#pragma unroll
        for (int j = 0; j < J; ++j){
            f32x4 z = {0.f, 0.f, 0.f, 0.f};
            acc[i][j] = z;
        }

    for (int st = 0; st < NSTEPS; ++st){
        const int cur = st & 1, nxt = cur ^ 1;
        s16x8 ra[QA], rb[QB];
        if (st + 1 < NSTEPS){
#pragma unroll
            for (int q = 0; q < QA; ++q)
                ra[q] = *(const s16x8*)(A + (size_t)aRow(ar[q],st+1)*EP + aCol(st+1) + ao[q]);
#pragma unroll
            for (int q = 0; q < QB; ++q)
                rb[q] = *(const s16x8*)(B + (size_t)bRow(brr[q],st+1)*EP + aCol(st+1) + bro[q]);
        }
        s16x8 af[I], bfr[J];
#pragma unroll
        for (int i = 0; i < I; ++i)
            af[i] = *(const s16x8*)&Al[cur][w*WR + i*16 + fr][kfo];
#pragma unroll
        for (int j = 0; j < J; ++j)
            bfr[j] = *(const s16x8*)&Bl[cur][j*16 + fr][kfo];
#pragma unroll
        for (int i = 0; i < I; ++i)
#pragma unroll
            for (int j = 0; j < J; ++j)
                acc[i][j] = __builtin_amdgcn_mfma_f32_16x16x32_bf16(af[i], bfr[j], acc[i][j], 0, 0, 0);
        if (st + 1 < NSTEPS){
#pragma unroll
            for (int q = 0; q < QA; ++q) *(s16x8*)&Al[nxt][ar[q]][ao[q]] = ra[q];
#pragma unroll
            for (int q = 0; q < QB; ++q) *(s16x8*)&Bl[nxt][brr[q]][bro[q]] = rb[q];
        }
        __syncthreads();
    }

#pragma unroll
    for (int i = 0; i < I; ++i){
#pragma unroll
        for (int j = 0; j < J; ++j){
            int col = n0 + j*16 + fr;
            if (col < EP){
                float bs = (col < E_) ? bias[col] : 0.f;
#pragma unroll
                for (int r = 0; r < 4; ++r){
                    int rowg = m_base + w*WR + i*16 + ((lane >> 4) << 2) + r;
                    float v = acc[i][j][r] + bs;
                    if constexpr (MODE == 1){
                        v = v > 0.f ? v : 0.f;
                    } else if constexpr (MODE == 0){
                        v = v > 0.f ? 1.0507009873554805f * v
                                    : 1.7580993408473766f * (__expf(v) - 1.f);
                    } else {
                        v += b2f(gadd16[(size_t)rowg*EP + col]);   // bf16 residual, pad=0
                        v *= LOG2E;
                    }
                    if constexpr (TRANSP){
                        Obf[(size_t)(col >> 5)*SLAB + (size_t)rowg*32 + (col & 31)] = f2b(v);
                    } else {
                        Obf[(size_t)rowg*EP + col] = f2b(v);
                    }
                }
            }
        }
    }
}

template<int MODE, int BM, int BN, int TRANSP>
__global__ __launch_bounds__(256, 2)
void k_gemm(const u16* __restrict__ A, const u16* __restrict__ B,
            u16* __restrict__ Obf, const float* __restrict__ bias,
            const u16* __restrict__ gadd16, int dil)
{
    extern __shared__ char smem[];
    gemm_body<MODE,BM,BN,TRANSP>(smem, blockIdx.x, blockIdx.y, A, B, Obf, bias, gadd16, dil);
}

// two independent GEMMs in one launch (block-range dispatch)
template<int MA,int BMa,int BNa, int MB,int BMb,int BNb>
__global__ __launch_bounds__(256, 2)
void k_gemm_dual(int nA, int gxA, int gxB,
            const u16* Aa, const u16* Ba, u16* Oa, const float* ba, const u16* ga, int da,
            const u16* Ab, const u16* Bb, u16* Ob, const float* bb, const u16* gb, int db)
{
    extern __shared__ char smem[];
    int bid = blockIdx.x;
    if (bid < nA){
        gemm_body<MA,BMa,BNa,0>(smem, bid % gxA, bid / gxA, Aa, Ba, Oa, ba, ga, da);
    } else {
        int b2 = bid - nA;
        gemm_body<MB,BMb,BNb,0>(smem, b2 % gxB, b2 / gxB, Ab, Bb, Ob, bb, gb, db);
    }
}

// ---------------- fused scores GEMM + softmax-weighted mean ----------------
// R11-exact (known good, 94.9us): A k-major slabs; B in LDS in MFMA FRAGMENT
// ORDER [st][j][lane] (zero bank conflicts); BN=128, grid (222,4); 1-step A
// prefetch; max-free exp2 epilogue; per-chunk 2-barrier combine.

__global__ __launch_bounds__(256, 2)
void k_scores(const u16* __restrict__ A, const u16* __restrict__ B,
              float* __restrict__ xf, float* __restrict__ zt)
{
    __shared__ s16x8 Blf[3584];            // 7 st x 8 j x 64 lane = 56 KB
    __shared__ float red[2][4][128];       // 4 KB

    const int tid  = threadIdx.x;
    const int lane = tid & 63;
    const int w    = tid >> 6;
    const int fr   = lane & 15;
    const int kfo  = (lane >> 4) * 8;
    const int n0   = blockIdx.x * 128;
    const int b    = blockIdx.y;

    // k-major A: addr = st*SLAB + row*32 + kfo
    const u16* Abase = A + (size_t)(b*256 + w*64 + fr)*32 + kfo;

    // prefetch (ci=0, st=0) before staging B
    s16x8 cur[4], nxt[4];
#pragma unroll
    for (int i = 0; i < 4; ++i)
        cur[i] = *(const s16x8*)(Abase + (size_t)(i*16)*32);

    // stage B panel in fragment order: entry v = (st*8+j)*64 + ln
#pragma unroll
    for (int q = 0; q < 14; ++q){
        int v    = q*256 + tid;
        int st   = v >> 9;
        int rem  = v & 511;
        int j    = rem >> 6;
        int ln2  = rem & 63;
        int fr2  = ln2 & 15, kg = ln2 >> 4;
        Blf[v] = *(const s16x8*)(B + (size_t)(n0 + j*16 + fr2)*EP + st*32 + kg*8);
    }
    __syncthreads();

    float xsum = 0.f;

#pragma unroll
    for (int ci = 0; ci < 5; ++ci){
        const u16* Ac = Abase + (size_t)(ci*4*256)*32;

        f32x4 acc[4][8];
#pragma unroll
        for (int i = 0; i < 4; ++i)
#pragma unroll
            for (int j = 0; j < 8; ++j){
                f32x4 z = {0.f, 0.f, 0.f, 0.f};
                acc[i][j] = z;
            }

#pragma unroll
        for (int st = 0; st < 7; ++st){
            const bool last = (ci == 4) && (st == 6);
            if (!last){
                const u16* An = (st < 6) ? (Ac + (size_t)(st+1)*SLAB)
                                         : (Ac + (size_t)(4*256)*32);
#pragma unroll
                for (int i = 0; i < 4; ++i)
                    nxt[i] = *(const s16x8*)(An + (size_t)(i*16)*32);
            }
            s16x8 bfr[8];
#pragma unroll
            for (int j = 0; j < 8; ++j)
                bfr[j] = Blf[(st*8 + j)*64 + lane];
#pragma unroll
            for (int i = 0; i < 4; ++i)
#pragma unroll
                for (int j = 0; j < 8; ++j)
                    acc[i][j] = __builtin_amdgcn_mfma_f32_16x16x32_bf16(cur[i], bfr[j], acc[i][j], 0, 0, 0);
            if (!last){
#pragma unroll
                for (int i = 0; i < 4; ++i) cur[i] = nxt[i];
            }
        }

        __syncthreads();   // red free (previous chunk's combine done)
        // max-free epilogue (log2-domain scores, |v| small -> exp2 safe)
#pragma unroll
        for (int j = 0; j < 8; ++j){
            float se = 0.f, sv = 0.f;
#pragma unroll
            for (int i = 0; i < 4; ++i)
#pragma unroll
                for (int r = 0; r < 4; ++r){
                    int row = w*64 + i*16 + ((lane >> 4) << 2) + r;
                    if (row < 244){
                        float v = acc[i][j][r];
                        float e = fexp2(v);
                        se += e; sv += e * v;
                    }
                }
            se += __shfl_xor(se, 16); se += __shfl_xor(se, 32);
            sv += __shfl_xor(sv, 16); sv += __shfl_xor(sv, 32);
            if (lane < 16){
                int cc = j*16 + lane;
                red[0][w][cc] = se;
                red[1][w][cc] = sv;
            }
        }
        __syncthreads();
        if (tid < 128){
            float SE = 0.f, SV = 0.f;
#pragma unroll
            for (int ww = 0; ww < 4; ++ww){
                SE += red[0][ww][tid];
                SV += red[1][ww][tid];
            }
            xsum += SV / SE;
        }
    }

    if (tid < 128){
        int n = n0 + tid;
        if (n < NL){
            float v = xsum * LN2;
            xf[(size_t)b*NLP + n] = v;
            zt[(size_t)n*4 + b] = 1.f / (1.f + __expf(-v));   // transposed sigmoid
        }
    }
}

// ---------------- CorNet ----------------
// cord: grid (CORN, 2) — block (j,h) dots wd row-half with zt (float4 both
// sides; head/tail scalars fix odd-NL row alignment). Raw partials -> pcb.

__global__ void k_cord(const float4* __restrict__ zt, const float* __restrict__ wd,
                       float4* __restrict__ pcb){
    int j = blockIdx.x, h = blockIdx.y, t = threadIdx.x;
    const float* wr = wd + (size_t)j*NL;
    int base_n = h*NHALF;
    int end_n  = (h == 0) ? NHALF : NL;
    float a0=0.f, a1=0.f, a2=0.f, a3=0.f;

    int mis  = (int)(((size_t)j*NL + base_n) & 3);
    int lead = (4 - mis) & 3;
    if (lead > end_n - base_n) lead = end_n - base_n;
    if (t < lead){
        int n = base_n + t;
        float wv = wr[n];
        float4 zz = zt[n];
        a0 = wv*zz.x; a1 = wv*zz.y; a2 = wv*zz.z; a3 = wv*zz.w;
    }
    int vstart = base_n + lead;
    int nv = (end_n - vstart) >> 2;
    const float4* wv4 = (const float4*)(wr + vstart);
    for (int i = t; i < nv; i += 256){
        float4 wq = wv4[i];
        int n = vstart + i*4;
        float4 z0 = zt[n], z1 = zt[n+1], z2 = zt[n+2], z3 = zt[n+3];
        a0 += wq.x*z0.x + wq.y*z1.x + wq.z*z2.x + wq.w*z3.x;
        a1 += wq.x*z0.y + wq.y*z1.y + wq.z*z2.y + wq.w*z3.y;
        a2 += wq.x*z0.z + wq.y*z1.z + wq.z*z2.z + wq.w*z3.z;
        a3 += wq.x*z0.w + wq.y*z1.w + wq.z*z2.w + wq.w*z3.w;
    }
    int tstart = vstart + nv*4;
    if (t < end_n - tstart){
        int n = tstart + t;
        float wv = wr[n];
        float4 zz = zt[n];
        a0 += wv*zz.x; a1 += wv*zz.y; a2 += wv*zz.z; a3 += wv*zz.w;
    }

    __shared__ float r[4][256];
    r[0][t]=a0; r[1][t]=a1; r[2][t]=a2; r[3][t]=a3;
    __syncthreads();
    for (int s = 128; s > 0; s >>= 1){
        if (t < s){
            r[0][t]+=r[0][t+s]; r[1][t]+=r[1][t+s];
            r[2][t]+=r[2][t+s]; r[3][t]+=r[3][t+s];
        }
        __syncthreads();
    }
    if (t == 0){
        float4 o; o.x=r[0][0]; o.y=r[1][0]; o.z=r[2][0]; o.w=r[3][0];
        pcb[(size_t)h*CORN + j] = o;
    }
}

// corc: 1776 blocks (4 rows/wave) for latency-hiding occupancy; staging
// combines pcb halves + bias + ELU; FINAL=0 writes xf + zt.
template<int FINAL>
__global__ void k_corc(const float4* __restrict__ pcb, const float* __restrict__ bd,
                       const float* __restrict__ wc, const float* __restrict__ bc,
                       float* __restrict__ xf, float4* __restrict__ zt,
                       float* __restrict__ dout){
    __shared__ float4 cl[CORN];
    int t = threadIdx.x;
    for (int i = t; i < CORN; i += 256){
        float4 s0 = pcb[i], s1 = pcb[CORN + i];
        float bdv = bd[i];
        float4 c;
        c.x = s0.x + s1.x + bdv; c.x = c.x > 0.f ? c.x : (__expf(c.x) - 1.f);
        c.y = s0.y + s1.y + bdv; c.y = c.y > 0.f ? c.y : (__expf(c.y) - 1.f);
        c.z = s0.z + s1.z + bdv; c.z = c.z > 0.f ? c.z : (__expf(c.z) - 1.f);
        c.w = s0.w + s1.w + bdv; c.w = c.w > 0.f ? c.w : (__expf(c.w) - 1.f);
        cl[i] = c;
    }
    __syncthreads();
    int w = t >> 6, ln = t & 63;
    for (int r = 0; r < 4; ++r){
        int n = blockIdx.x*16 + w*4 + r;
        if (n >= NL) continue;
        const float4* wr4 = (const float4*)(wc + (size_t)n*CORN);
        float a0=0.f, a1=0.f, a2=0.f, a3=0.f;
#pragma unroll
        for (int it = 0; it < 4; ++it){
            int j4 = ln + it*64;
            if (j4 < 250){
                float4 w4 = wr4[j4];
                float4 c0 = cl[j4*4+0], c1 = cl[j4*4+1], c2 = cl[j4*4+2], c3 = cl[j4*4+3];
                a0 += w4.x*c0.x + w4.y*c1.x + w4.z*c2.x + w4.w*c3.x;
                a1 += w4.x*c0.y + w4.y*c1.y + w4.z*c2.y + w4.w*c3.y;
                a2 += w4.x*c0.z + w4.y*c1.z + w4.z*c2.z + w4.w*c3.z;
                a3 += w4.x*c0.w + w4.y*c1.w + w4.z*c2.w + w4.w*c3.w;
            }
        }
#pragma unroll
        for (int o = 32; o > 0; o >>= 1){
            a0 += __shfl_xor(a0, o);
            a1 += __shfl_xor(a1, o);
            a2 += __shfl_xor(a2, o);
            a3 += __shfl_xor(a3, o);
        }
        if (ln == 0){
            float base = bc[n];
            float v0 = a0 + base + xf[0*(size_t)NLP + n];
            float v1 = a1 + base + xf[1*(size_t)NLP + n];
            float v2 = a2 + base + xf[2*(size_t)NLP + n];
            float v3 = a3 + base + xf[3*(size_t)NLP + n];
            if (FINAL){
                dout[0*(size_t)NL + n] = v0;
                dout[1*(size_t)NL + n] = v1;
                dout[2*(size_t)NL + n] = v2;
                dout[3*(size_t)NL + n] = v3;
            } else {
                xf[0*(size_t)NLP + n] = v0;
                xf[1*(size_t)NLP + n] = v1;
                xf[2*(size_t)NLP + n] = v2;
                xf[3*(size_t)NLP + n] = v3;
                float4 zz;
                zz.x = 1.f / (1.f + __expf(-v0));
                zz.y = 1.f / (1.f + __expf(-v1));
                zz.z = 1.f / (1.f + __expf(-v2));
                zz.w = 1.f / (1.f + __expf(-v3));
                zt[n] = zz;
            }
        }
    }
}

// ---------------- host launch ----------------

extern "C" void kernel_launch(void* const* d_in, const int* in_sizes, int n_in,
                              void* d_out, int out_size, void* d_ws, size_t ws_size,
                              hipStream_t stream){
    (void)in_sizes; (void)n_in; (void)out_size; (void)ws_size;
    const int* t0 = (const int*)d_in[0];
    const int* t1 = (const int*)d_in[1];
    const int* t2 = (const int*)d_in[2];
    const int* t3 = (const int*)d_in[3];
    const int* t4 = (const int*)d_in[4];
    const int* src = (const int*)d_in[5];
    const int* dst = (const int*)d_in[6];
    const float* g    = (const float*)d_in[7];
    const float* emb  = (const float*)d_in[8];
    const float* cw1 = (const float*)d_in[9];  const float* cb1 = (const float*)d_in[10];
    const float* cw2 = (const float*)d_in[11]; const float* cb2 = (const float*)d_in[12];
    const float* cw3 = (const float*)d_in[13]; const float* cb3 = (const float*)d_in[14];
    const float* gw1 = (const float*)d_in[15]; const float* gb1 = (const float*)d_in[16];
    const float* gw2 = (const float*)d_in[17]; const float* gb2 = (const float*)d_in[18];
    const float* wd1 = (const float*)d_in[19]; const float* bd1 = (const float*)d_in[20];
    const float* wc1 = (const float*)d_in[21]; const float* bc1 = (const float*)d_in[22];
    const float* wd2 = (const float*)d_in[23]; const float* bd2 = (const float*)d_in[24];
    const float* wc2 = (const float*)d_in[25]; const float* bc2 = (const float*)d_in[26];

    char* p = (char*)d_ws;
    auto alloc = [&](size_t bytes)->char* {
        char* r = p;
        p += (bytes + 255) & ~(size_t)255;
        return r;
    };
    u16* gbf = (u16*)alloc((size_t)NLP*EP*2);
    u16* h1  = (u16*)alloc((size_t)NLP*EP*2);
    u16* agg = (u16*)alloc((size_t)NLP*EP*2);
    u16* lfb = (u16*)alloc((size_t)NLP*EP*2);
    u16* xA  = (u16*)alloc((size_t)MROWS*EP*2);
    u16* xB  = (u16*)alloc((size_t)MROWS*EP*2);
    u16* wcv1 = (u16*)alloc((size_t)768*EP*2);
    u16* wcv2 = (u16*)alloc((size_t)768*EP*2);
    u16* wcv3 = (u16*)alloc((size_t)768*EP*2);
    u16* wdn1 = (u16*)alloc((size_t)256*EP*2);
    u16* wdn2 = (u16*)alloc((size_t)256*EP*2);
    float* xf = (float*)alloc((size_t)4*NLP*4);
    float* zt = (float*)alloc((size_t)NLP*4*4);       // transposed sigmoid [n][4]
    float* pcb = (float*)alloc((size_t)2*CORN*4*4);   // cord partials [2][CORN][4]
    int* deg  = (int*)alloc((size_t)NLP*4);
    int* rp   = (int*)alloc((size_t)(NLP+1)*4);
    int* cur  = (int*)alloc((size_t)NLP*4);
    int* esrc = (int*)alloc((size_t)NEDGE*4);

    hipMemsetAsync(deg, 0, (size_t)NLP*4, stream);

    // fused prep + degree count
    PrepArgs pa{ g, gbf, gw1, wdn1, gw2, wdn2, cw1, wcv1, cw2, wcv2, cw3, wcv3,
                 t0, t1, t2, t3, t4, emb, xA };
    k_prep_all<<<PREP_TOT + 1776, 256, 0, stream>>>(pa, dst, deg);

    // CSR build: single-block scan, then scatter
    k_scan<<<1, 1024, 0, stream>>>(deg, rp, cur);
    k_scatter<<<1776, 256, 0, stream>>>(src, dst, cur, esrc);

    const int SM_D = (2*64*40 + 2*64*40)*2;    // 20480

    // LabelNet + conv chain, independent paths overlapped in dual launches
    k_agg<<<(NL+7)/8, 256, 0, stream>>>(gbf, rp, esrc, agg);
    k_gemm_dual<1,64,64, 0,64,64><<<1776+320, 256, SM_D, stream>>>(
        1776, 4, 4,
        agg, wdn1, h1, gb1, nullptr, 0,
        xA,  wcv1, xB, cb1, nullptr, 1);
    k_agg<<<(NL+7)/8, 256, 0, stream>>>(h1, rp, esrc, agg);
    k_gemm_dual<2,64,64, 0,64,64><<<1776+320, 256, SM_D, stream>>>(
        1776, 4, 4,
        agg, wdn2, lfb, gb2, gbf, 0,
        xB,  wcv2, xA,  cb2, nullptr, 2);
    // conv3: write k-major slabs for k_scores
    k_gemm<0,64,64,1><<<dim3(4,80), 256, SM_D, stream>>>(xA, wcv3, xB, cb3, nullptr, 3);

    // fused scores GEMM + softmax-weighted mean + transposed sigmoid
    k_scores<<<dim3(222, 4), 256, 0, stream>>>(xB, lfb, xf, zt);

    // CorNet x2 (split-n cord partials, combine+bias+ELU in corc staging)
    k_cord<<<dim3(CORN, 2), 256, 0, stream>>>((const float4*)zt, wd1, (float4*)pcb);
    k_corc<0><<<1776, 256, 0, stream>>>((const float4*)pcb, bd1, wc1, bc1, xf, (float4*)zt, nullptr);
    k_cord<<<dim3(CORN, 2), 256, 0, stream>>>((const float4*)zt, wd2, (float4*)pcb);
    k_corc<1><<<1776, 256, 0, stream>>>((const float4*)pcb, bd2, wc2, bc2, xf, nullptr, (float*)d_out);
}

// Round 16
// 433.952 us; speedup vs baseline: 1.1152x; 1.1152x over previous
//
#include <hip/hip_runtime.h>
#include <math.h>

#define E_      200
#define EP      224      // K padded to 7*32
#define NL      28415
#define NLP     28416
#define L0      256
#define MROWS   5120     // 20*256
#define CORN    1000
#define NEDGE   454640
#define LOG2E   1.44269504088896f
#define LN2     0.69314718055994531f
#define PREP_TOT 36352   // NLP + 512 + 2304 + MROWS
#define SLAB    (MROWS*32)   // k-major slab stride (elements)
#define NHALF   14208        // NLP/2

typedef unsigned short u16;
typedef __attribute__((ext_vector_type(8))) short s16x8;
typedef __attribute__((ext_vector_type(4))) float f32x4;

__device__ __forceinline__ u16 f2b(float f){
    unsigned u = __float_as_uint(f);
    unsigned r = (u + 0x7fffu + ((u >> 16) & 1u)) >> 16;
    return (u16)r;
}
__device__ __forceinline__ float b2f(u16 h){ return __uint_as_float(((unsigned)h) << 16); }

__device__ __forceinline__ float fexp2(float x){
    float r; asm("v_exp_f32 %0, %1" : "=v"(r) : "v"(x)); return r;
}

// ---------------- fused prep kernel (+ degree count) ----------------

struct PrepArgs {
    const float* g;   u16* gbf;
    const float* gw1; u16* wdn1;
    const float* gw2; u16* wdn2;
    const float* cw1; u16* wcv1;
    const float* cw2; u16* wcv2;
    const float* cw3; u16* wcv3;
    const int* t0; const int* t1; const int* t2; const int* t3; const int* t4;
    const float* emb; u16* xA;
};

__global__ void k_prep_all(PrepArgs a, const int* __restrict__ dste, int* __restrict__ deg){
    int bid = blockIdx.x;
    int t = threadIdx.x;
    if (bid >= PREP_TOT){           // degree-count blocks
        int e = (bid - PREP_TOT)*256 + t;
        if (e < NEDGE) atomicAdd(&deg[dste[e]], 1);
        return;
    }
    int e = t;
    if (e >= EP) return;
    if (bid < NLP){
        int n = bid;
        float v = (n < NL && e < E_) ? a.g[(size_t)n*E_ + e] : 0.f;
        a.gbf[(size_t)n*EP + e] = f2b(v);
        return;
    }
    bid -= NLP;
    if (bid < 512){
        const float* w = (bid < 256) ? a.gw1 : a.gw2;
        u16* out = (bid < 256) ? a.wdn1 : a.wdn2;
        int o = bid & 255;
        float v = (o < E_ && e < E_) ? w[(size_t)o*E_ + e] : 0.f;
        out[(size_t)o*EP + e] = f2b(v);
        return;
    }
    bid -= 512;
    if (bid < 2304){
        int which = bid / 768;
        const float* w = (which==0) ? a.cw1 : (which==1) ? a.cw2 : a.cw3;
        u16* out = (which==0) ? a.wcv1 : (which==1) ? a.wcv2 : a.wcv3;
        int r = bid - which*768;
        int kk = r >> 8, o = r & 255;
        float v = (o < E_ && e < E_) ? w[((size_t)o*E_ + e)*3 + kk] : 0.f;
        out[(size_t)r*EP + e] = f2b(v);
        return;
    }
    bid -= 2304;
    {   // embed
        int chunk = bid >> 8, l = bid & 255, s = chunk >> 2, b = chunk & 3;
        const int* tp = (s==0)?a.t0:(s==1)?a.t1:(s==2)?a.t2:(s==3)?a.t3:a.t4;
        int tok = tp[b*L0 + l];
        float v = (e < E_) ? a.emb[(size_t)tok*E_ + e] : 0.f;
        a.xA[(size_t)bid*EP + e] = f2b(v);
    }
}

// ---------------- CSR build (parallel 2-kernel scan) ----------------

__global__ void k_scan1(const int* __restrict__ deg, int* __restrict__ part){
    __shared__ int s[256];
    int t = threadIdx.x;
    int idx = blockIdx.x*256 + t;
    int v = (idx < NLP) ? deg[idx] : 0;
    s[t] = v;
    __syncthreads();
    for (int o = 128; o > 0; o >>= 1){
        if (t < o) s[t] += s[t+o];
        __syncthreads();
    }
    if (t == 0) part[blockIdx.x] = s[0];
}

// every block redundantly scans the 111 partials, then block-local scan
__global__ void k_scan23(const int* __restrict__ deg, const int* __restrict__ part,
                         int* __restrict__ rowptr, int* __restrict__ cursor){
    __shared__ int s[256];
    __shared__ int sp[128];
    int t = threadIdx.x;
    if (t < 128) sp[t] = (t < 111) ? part[t] : 0;
    __syncthreads();
    for (int o = 1; o < 128; o <<= 1){
        int x = (t < 128 && t >= o) ? sp[t-o] : 0;
        __syncthreads();
        if (t < 128) sp[t] += x;
        __syncthreads();
    }
    int idx = blockIdx.x*256 + t;
    int v = (idx < NLP) ? deg[idx] : 0;
    s[t] = v;
    __syncthreads();
    for (int o = 1; o < 256; o <<= 1){
        int x = (t >= o) ? s[t-o] : 0;
        __syncthreads();
        s[t] += x;
        __syncthreads();
    }
    int bofs = sp[blockIdx.x] - part[blockIdx.x];
    int excl = s[t] - v + bofs;
    if (idx < NLP){ rowptr[idx] = excl; cursor[idx] = excl; }
    if (idx == NLP-1) rowptr[NLP] = excl + v;
}

__global__ void k_scatter(const int* __restrict__ src, const int* __restrict__ dst,
                          int* __restrict__ cursor, int* __restrict__ esrc){
    int e = blockIdx.x*256 + threadIdx.x;
    if (e < NEDGE){
        int p = atomicAdd(&cursor[dst[e]], 1);
        esrc[p] = src[e];
    }
}

// half-wave (32 lanes, 28 active) per node; 8-edge unroll (8 loads in flight)
__global__ void k_agg(const u16* __restrict__ feat, const int* __restrict__ rp,
                      const int* __restrict__ esrc, u16* __restrict__ out){
    int half = threadIdx.x >> 5;
    int ln   = threadIdx.x & 31;
    int n = blockIdx.x*8 + half;
    if (n >= NL || ln >= 28) return;
    int beg = rp[n], end = rp[n+1];
    float acc0[8] = {0,0,0,0,0,0,0,0};
    float acc1[8] = {0,0,0,0,0,0,0,0};
    int i = beg;
    for (; i + 7 < end; i += 8){
        int s0 = esrc[i],   s1 = esrc[i+1], s2 = esrc[i+2], s3 = esrc[i+3];
        int s4 = esrc[i+4], s5 = esrc[i+5], s6 = esrc[i+6], s7 = esrc[i+7];
        s16x8 v0 = *(const s16x8*)(feat + (size_t)s0*EP + ln*8);
        s16x8 v1 = *(const s16x8*)(feat + (size_t)s1*EP + ln*8);
        s16x8 v2 = *(const s16x8*)(feat + (size_t)s2*EP + ln*8);
        s16x8 v3 = *(const s16x8*)(feat + (size_t)s3*EP + ln*8);
        s16x8 v4 = *(const s16x8*)(feat + (size_t)s4*EP + ln*8);
        s16x8 v5 = *(const s16x8*)(feat + (size_t)s5*EP + ln*8);
        s16x8 v6 = *(const s16x8*)(feat + (size_t)s6*EP + ln*8);
        s16x8 v7 = *(const s16x8*)(feat + (size_t)s7*EP + ln*8);
#pragma unroll
        for (int j = 0; j < 8; ++j){
            acc0[j] += (b2f((u16)v0[j]) + b2f((u16)v2[j])) + (b2f((u16)v4[j]) + b2f((u16)v6[j]));
            acc1[j] += (b2f((u16)v1[j]) + b2f((u16)v3[j])) + (b2f((u16)v5[j]) + b2f((u16)v7[j]));
        }
    }
    for (; i + 1 < end; i += 2){
        int s0 = esrc[i], s1 = esrc[i+1];
        s16x8 v0 = *(const s16x8*)(feat + (size_t)s0*EP + ln*8);
        s16x8 v1 = *(const s16x8*)(feat + (size_t)s1*EP + ln*8);
#pragma unroll
        for (int j = 0; j < 8; ++j){
            acc0[j] += b2f((u16)v0[j]);
            acc1[j] += b2f((u16)v1[j]);
        }
    }
    if (i < end){
        int s0 = esrc[i];
        s16x8 v0 = *(const s16x8*)(feat + (size_t)s0*EP + ln*8);
#pragma unroll
        for (int j = 0; j < 8; ++j) acc0[j] += b2f((u16)v0[j]);
    }
    s16x8 o;
#pragma unroll
    for (int j = 0; j < 8; ++j) o[j] = (short)f2b(acc0[j] + acc1[j]);
    *(s16x8*)(out + (size_t)n*EP + ln*8) = o;
}

// ---------------- MFMA GEMM body (modes 0/1/2) ----------------
// TRANSP=1 (mode 0 only): write output in k-major slabs [7][MROWS][32]
// MODE 2: residual add reads bf16 gbf (padded zeros) -> branchless

template<int MODE, int BM, int BN, int TRANSP>
__device__ __forceinline__ void gemm_body(char* smem, int bx, int by,
            const u16* __restrict__ A, const u16* __restrict__ B,
            u16* __restrict__ Obf, const float* __restrict__ bias,
            const u16* __restrict__ gadd16, int dil)
{
    constexpr int NSTEPS = (MODE == 0) ? 21 : 7;
    constexpr int QA = (BM*4)/256, QB = (BN*4)/256, I = BM/64, J = BN/16, WR = BM/4;
    typedef u16 (*AlT)[BM][40];
    typedef u16 (*BlT)[BN][40];
    AlT Al = (AlT)smem;
    BlT Bl = (BlT)(smem + (size_t)2*BM*40*2);

    const int tid  = threadIdx.x;
    const int lane = tid & 63;
    const int w    = tid >> 6;
    const int fr   = lane & 15;
    const int kfo  = (lane >> 4) * 8;
    const int n0     = bx * BN;
    const int m_base = by * BM;

    int ar[QA], ao[QA], brr[QB], bro[QB];
#pragma unroll
    for (int q = 0; q < QA; ++q){ int idx = q*256 + tid; ar[q] = idx >> 2; ao[q] = (idx & 3)*8; }
#pragma unroll
    for (int q = 0; q < QB; ++q){ int idx = q*256 + tid; brr[q] = idx >> 2; bro[q] = (idx & 3)*8; }

    auto aRow = [&](int row, int st)->int {
        if constexpr (MODE == 0){
            int off = (m_base & 255) + row + (st/7)*dil;
            if (off > 255) off = 255;
            return (m_base & ~255) + off;
        } else return m_base + row;
    };
    auto aCol = [&](int st)->int {
        if constexpr (MODE == 0) return (st % 7) * 32; else return st * 32;
    };
    auto bRow = [&](int row, int st)->int {
        if constexpr (MODE == 0) return (st/7)*256 + n0 + row; else return n0 + row;
    };

#pragma unroll
    for (int q = 0; q < QA; ++q){
        s16x8 v = *(const s16x8*)(A + (size_t)aRow(ar[q],0)*EP + aCol(0) + ao[q]);
        *(s16x8*)&Al[0][ar[q]][ao[q]] = v;
    }
#pragma unroll
    for (int q = 0; q < QB; ++q){
        s16x8 v = *(const s16x8*)(B + (size_t)bRow(brr[q],0)*EP + aCol(0) + bro[q]);
        *(s16x8*)&Bl[0][brr[q]][bro[q]] = v;
    }
    __syncthreads();

    f32x4 acc[I][J];
#pragma unroll
    for (int i = 0; i < I; ++i)
#pragma unroll
        for (int j = 0; j < J; ++j){
            f32x4 z = {0.f, 0.f, 0.f, 0.f};
            acc[i][j] = z;
        }

    for (int st = 0; st < NSTEPS; ++st){
        const int cur = st & 1, nxt = cur ^ 1;
        s16x8 ra[QA], rb[QB];
        if (st + 1 < NSTEPS){
#pragma unroll
            for (int q = 0; q < QA; ++q)
                ra[q] = *(const s16x8*)(A + (size_t)aRow(ar[q],st+1)*EP + aCol(st+1) + ao[q]);
#pragma unroll
            for (int q = 0; q < QB; ++q)
                rb[q] = *(const s16x8*)(B + (size_t)bRow(brr[q],st+1)*EP + aCol(st+1) + bro[q]);
        }
        s16x8 af[I], bfr[J];
#pragma unroll
        for (int i = 0; i < I; ++i)
            af[i] = *(const s16x8*)&Al[cur][w*WR + i*16 + fr][kfo];
#pragma unroll
        for (int j = 0; j < J; ++j)
            bfr[j] = *(const s16x8*)&Bl[cur][j*16 + fr][kfo];
#pragma unroll
        for (int i = 0; i < I; ++i)
#pragma unroll
            for (int j = 0; j < J; ++j)
                acc[i][j] = __builtin_amdgcn_mfma_f32_16x16x32_bf16(af[i], bfr[j], acc[i][j], 0, 0, 0);
        if (st + 1 < NSTEPS){
#pragma unroll
            for (int q = 0; q < QA; ++q) *(s16x8*)&Al[nxt][ar[q]][ao[q]] = ra[q];
#pragma unroll
            for (int q = 0; q < QB; ++q) *(s16x8*)&Bl[nxt][brr[q]][bro[q]] = rb[q];
        }
        __syncthreads();
    }

#pragma unroll
    for (int i = 0; i < I; ++i){
#pragma unroll
        for (int j = 0; j < J; ++j){
            int col = n0 + j*16 + fr;
            if (col < EP){
                float bs = (col < E_) ? bias[col] : 0.f;
#pragma unroll
                for (int r = 0; r < 4; ++r){
                    int rowg = m_base + w*WR + i*16 + ((lane >> 4) << 2) + r;
                    float v = acc[i][j][r] + bs;
                    if constexpr (MODE == 1){
                        v = v > 0.f ? v : 0.f;
                    } else if constexpr (MODE == 0){
                        v = v > 0.f ? 1.0507009873554805f * v
                                    : 1.7580993408473766f * (__expf(v) - 1.f);
                    } else {
                        v += b2f(gadd16[(size_t)rowg*EP + col]);   // bf16 residual, pad=0
                        v *= LOG2E;
                    }
                    if constexpr (TRANSP){
                        Obf[(size_t)(col >> 5)*SLAB + (size_t)rowg*32 + (col & 31)] = f2b(v);
                    } else {
                        Obf[(size_t)rowg*EP + col] = f2b(v);
                    }
                }
            }
        }
    }
}

template<int MODE, int BM, int BN, int TRANSP>
__global__ __launch_bounds__(256, 2)
void k_gemm(const u16* __restrict__ A, const u16* __restrict__ B,
            u16* __restrict__ Obf, const float* __restrict__ bias,
            const u16* __restrict__ gadd16, int dil)
{
    extern __shared__ char smem[];
    gemm_body<MODE,BM,BN,TRANSP>(smem, blockIdx.x, blockIdx.y, A, B, Obf, bias, gadd16, dil);
}

// two independent GEMMs in one launch (block-range dispatch)
template<int MA,int BMa,int BNa, int MB,int BMb,int BNb>
__global__ __launch_bounds__(256, 2)
void k_gemm_dual(int nA, int gxA, int gxB,
            const u16* Aa, const u16* Ba, u16* Oa, const float* ba, const u16* ga, int da,
            const u16* Ab, const u16* Bb, u16* Ob, const float* bb, const u16* gb, int db)
{
    extern __shared__ char smem[];
    int bid = blockIdx.x;
    if (bid < nA){
        gemm_body<MA,BMa,BNa,0>(smem, bid % gxA, bid / gxA, Aa, Ba, Oa, ba, ga, da);
    } else {
        int b2 = bid - nA;
        gemm_body<MB,BMb,BNb,0>(smem, b2 % gxB, b2 / gxB, Ab, Bb, Ob, bb, gb, db);
    }
}

// ---------------- fused scores GEMM + softmax-weighted mean ----------------
// R11-exact (known good, 94.9us): A k-major slabs; B in LDS in MFMA FRAGMENT
// ORDER [st][j][lane] (zero bank conflicts); BN=128, grid (222,4); 1-step A
// prefetch; max-free exp2 epilogue; per-chunk 2-barrier combine.

__global__ __launch_bounds__(256, 2)
void k_scores(const u16* __restrict__ A, const u16* __restrict__ B,
              float* __restrict__ xf, float* __restrict__ zt)
{
    __shared__ s16x8 Blf[3584];            // 7 st x 8 j x 64 lane = 56 KB
    __shared__ float red[2][4][128];       // 4 KB

    const int tid  = threadIdx.x;
    const int lane = tid & 63;
    const int w    = tid >> 6;
    const int fr   = lane & 15;
    const int kfo  = (lane >> 4) * 8;
    const int n0   = blockIdx.x * 128;
    const int b    = blockIdx.y;

    // k-major A: addr = st*SLAB + row*32 + kfo
    const u16* Abase = A + (size_t)(b*256 + w*64 + fr)*32 + kfo;

    // prefetch (ci=0, st=0) before staging B
    s16x8 cur[4], nxt[4];
#pragma unroll
    for (int i = 0; i < 4; ++i)
        cur[i] = *(const s16x8*)(Abase + (size_t)(i*16)*32);

    // stage B panel in fragment order: entry v = (st*8+j)*64 + ln
#pragma unroll
    for (int q = 0; q < 14; ++q){
        int v    = q*256 + tid;
        int st   = v >> 9;
        int rem  = v & 511;
        int j    = rem >> 6;
        int ln2  = rem & 63;
        int fr2  = ln2 & 15, kg = ln2 >> 4;
        Blf[v] = *(const s16x8*)(B + (size_t)(n0 + j*16 + fr2)*EP + st*32 + kg*8);
    }
    __syncthreads();

    float xsum = 0.f;

#pragma unroll
    for (int ci = 0; ci < 5; ++ci){
        const u16* Ac = Abase + (size_t)(ci*4*256)*32;

        f32x4 acc[4][8];
#pragma unroll
        for (int i = 0; i < 4; ++i)
#pragma unroll
            for (int j = 0; j < 8; ++j){
                f32x4 z = {0.f, 0.f, 0.f, 0.f};
                acc[i][j] = z;
            }

#pragma unroll
        for (int st = 0; st < 7; ++st){
            const bool last = (ci == 4) && (st == 6);
            if (!last){
                const u16* An = (st < 6) ? (Ac + (size_t)(st+1)*SLAB)
                                         : (Ac + (size_t)(4*256)*32);
#pragma unroll
                for (int i = 0; i < 4; ++i)
                    nxt[i] = *(const s16x8*)(An + (size_t)(i*16)*32);
            }
            s16x8 bfr[8];
#pragma unroll
            for (int j = 0; j < 8; ++j)
                bfr[j] = Blf[(st*8 + j)*64 + lane];
#pragma unroll
            for (int i = 0; i < 4; ++i)
#pragma unroll
                for (int j = 0; j < 8; ++j)
                    acc[i][j] = __builtin_amdgcn_mfma_f32_16x16x32_bf16(cur[i], bfr[j], acc[i][j], 0, 0, 0);
            if (!last){
#pragma unroll
                for (int i = 0; i < 4; ++i) cur[i] = nxt[i];
            }
        }

        __syncthreads();   // red free (previous chunk's combine done)
        // max-free epilogue (log2-domain scores, |v| small -> exp2 safe)
#pragma unroll
        for (int j = 0; j < 8; ++j){
            float se = 0.f, sv = 0.f;
#pragma unroll
            for (int i = 0; i < 4; ++i)
#pragma unroll
                for (int r = 0; r < 4; ++r){
                    int row = w*64 + i*16 + ((lane >> 4) << 2) + r;
                    if (row < 244){
                        float v = acc[i][j][r];
                        float e = fexp2(v);
                        se += e; sv += e * v;
                    }
                }
            se += __shfl_xor(se, 16); se += __shfl_xor(se, 32);
            sv += __shfl_xor(sv, 16); sv += __shfl_xor(sv, 32);
            if (lane < 16){
                int cc = j*16 + lane;
                red[0][w][cc] = se;
                red[1][w][cc] = sv;
            }
        }
        __syncthreads();
        if (tid < 128){
            float SE = 0.f, SV = 0.f;
#pragma unroll
            for (int ww = 0; ww < 4; ++ww){
                SE += red[0][ww][tid];
                SV += red[1][ww][tid];
            }
            xsum += SV / SE;
        }
    }

    if (tid < 128){
        int n = n0 + tid;
        if (n < NL){
            float v = xsum * LN2;
            xf[(size_t)b*NLP + n] = v;
            zt[(size_t)n*4 + b] = 1.f / (1.f + __expf(-v));   // transposed sigmoid
        }
    }
}

// ---------------- CorNet ----------------
// cord: grid (CORN, 2) — block (j,h) dots wd row-half with zt (float4 both
// sides; head/tail scalars fix odd-NL row alignment). Raw partials -> pcb.

__global__ void k_cord(const float4* __restrict__ zt, const float* __restrict__ wd,
                       float4* __restrict__ pcb){
    int j = blockIdx.x, h = blockIdx.y, t = threadIdx.x;
    const float* wr = wd + (size_t)j*NL;
    int base_n = h*NHALF;
    int end_n  = (h == 0) ? NHALF : NL;
    float a0=0.f, a1=0.f, a2=0.f, a3=0.f;

    int mis  = (int)(((size_t)j*NL + base_n) & 3);
    int lead = (4 - mis) & 3;
    if (lead > end_n - base_n) lead = end_n - base_n;
    if (t < lead){
        int n = base_n + t;
        float wv = wr[n];
        float4 zz = zt[n];
        a0 = wv*zz.x; a1 = wv*zz.y; a2 = wv*zz.z; a3 = wv*zz.w;
    }
    int vstart = base_n + lead;
    int nv = (end_n - vstart) >> 2;
    const float4* wv4 = (const float4*)(wr + vstart);
    for (int i = t; i < nv; i += 256){
        float4 wq = wv4[i];
        int n = vstart + i*4;
        float4 z0 = zt[n], z1 = zt[n+1], z2 = zt[n+2], z3 = zt[n+3];
        a0 += wq.x*z0.x + wq.y*z1.x + wq.z*z2.x + wq.w*z3.x;
        a1 += wq.x*z0.y + wq.y*z1.y + wq.z*z2.y + wq.w*z3.y;
        a2 += wq.x*z0.z + wq.y*z1.z + wq.z*z2.z + wq.w*z3.z;
        a3 += wq.x*z0.w + wq.y*z1.w + wq.z*z2.w + wq.w*z3.w;
    }
    int tstart = vstart + nv*4;
    if (t < end_n - tstart){
        int n = tstart + t;
        float wv = wr[n];
        float4 zz = zt[n];
        a0 += wv*zz.x; a1 += wv*zz.y; a2 += wv*zz.z; a3 += wv*zz.w;
    }

    __shared__ float r[4][256];
    r[0][t]=a0; r[1][t]=a1; r[2][t]=a2; r[3][t]=a3;
    __syncthreads();
    for (int s = 128; s > 0; s >>= 1){
        if (t < s){
            r[0][t]+=r[0][t+s]; r[1][t]+=r[1][t+s];
            r[2][t]+=r[2][t+s]; r[3][t]+=r[3][t+s];
        }
        __syncthreads();
    }
    if (t == 0){
        float4 o; o.x=r[0][0]; o.y=r[1][0]; o.z=r[2][0]; o.w=r[3][0];
        pcb[(size_t)h*CORN + j] = o;
    }
}

// corc: 1776 blocks (4 rows/wave) for latency-hiding occupancy; staging
// combines pcb halves + bias + ELU; FINAL=0 writes xf + zt.
template<int FINAL>
__global__ void k_corc(const float4* __restrict__ pcb, const float* __restrict__ bd,
                       const float* __restrict__ wc, const float* __restrict__ bc,
                       float* __restrict__ xf, float4* __restrict__ zt,
                       float* __restrict__ dout){
    __shared__ float4 cl[CORN];
    int t = threadIdx.x;
    for (int i = t; i < CORN; i += 256){
        float4 s0 = pcb[i], s1 = pcb[CORN + i];
        float bdv = bd[i];
        float4 c;
        c.x = s0.x + s1.x + bdv; c.x = c.x > 0.f ? c.x : (__expf(c.x) - 1.f);
        c.y = s0.y + s1.y + bdv; c.y = c.y > 0.f ? c.y : (__expf(c.y) - 1.f);
        c.z = s0.z + s1.z + bdv; c.z = c.z > 0.f ? c.z : (__expf(c.z) - 1.f);
        c.w = s0.w + s1.w + bdv; c.w = c.w > 0.f ? c.w : (__expf(c.w) - 1.f);
        cl[i] = c;
    }
    __syncthreads();
    int w = t >> 6, ln = t & 63;
    for (int r = 0; r < 4; ++r){
        int n = blockIdx.x*16 + w*4 + r;
        if (n >= NL) continue;
        const float4* wr4 = (const float4*)(wc + (size_t)n*CORN);
        float a0=0.f, a1=0.f, a2=0.f, a3=0.f;
#pragma unroll
        for (int it = 0; it < 4; ++it){
            int j4 = ln + it*64;
            if (j4 < 250){
                float4 w4 = wr4[j4];
                float4 c0 = cl[j4*4+0], c1 = cl[j4*4+1], c2 = cl[j4*4+2], c3 = cl[j4*4+3];
                a0 += w4.x*c0.x + w4.y*c1.x + w4.z*c2.x + w4.w*c3.x;
                a1 += w4.x*c0.y + w4.y*c1.y + w4.z*c2.y + w4.w*c3.y;
                a2 += w4.x*c0.z + w4.y*c1.z + w4.z*c2.z + w4.w*c3.z;
                a3 += w4.x*c0.w + w4.y*c1.w + w4.z*c2.w + w4.w*c3.w;
            }
        }
#pragma unroll
        for (int o = 32; o > 0; o >>= 1){
            a0 += __shfl_xor(a0, o);
            a1 += __shfl_xor(a1, o);
            a2 += __shfl_xor(a2, o);
            a3 += __shfl_xor(a3, o);
        }
        if (ln == 0){
            float base = bc[n];
            float v0 = a0 + base + xf[0*(size_t)NLP + n];
            float v1 = a1 + base + xf[1*(size_t)NLP + n];
            float v2 = a2 + base + xf[2*(size_t)NLP + n];
            float v3 = a3 + base + xf[3*(size_t)NLP + n];
            if (FINAL){
                dout[0*(size_t)NL + n] = v0;
                dout[1*(size_t)NL + n] = v1;
                dout[2*(size_t)NL + n] = v2;
                dout[3*(size_t)NL + n] = v3;
            } else {
                xf[0*(size_t)NLP + n] = v0;
                xf[1*(size_t)NLP + n] = v1;
                xf[2*(size_t)NLP + n] = v2;
                xf[3*(size_t)NLP + n] = v3;
                float4 zz;
                zz.x = 1.f / (1.f + __expf(-v0));
                zz.y = 1.f / (1.f + __expf(-v1));
                zz.z = 1.f / (1.f + __expf(-v2));
                zz.w = 1.f / (1.f + __expf(-v3));
                zt[n] = zz;
            }
        }
    }
}

// ---------------- host launch ----------------

extern "C" void kernel_launch(void* const* d_in, const int* in_sizes, int n_in,
                              void* d_out, int out_size, void* d_ws, size_t ws_size,
                              hipStream_t stream){
    (void)in_sizes; (void)n_in; (void)out_size; (void)ws_size;
    const int* t0 = (const int*)d_in[0];
    const int* t1 = (const int*)d_in[1];
    const int* t2 = (const int*)d_in[2];
    const int* t3 = (const int*)d_in[3];
    const int* t4 = (const int*)d_in[4];
    const int* src = (const int*)d_in[5];
    const int* dst = (const int*)d_in[6];
    const float* g    = (const float*)d_in[7];
    const float* emb  = (const float*)d_in[8];
    const float* cw1 = (const float*)d_in[9];  const float* cb1 = (const float*)d_in[10];
    const float* cw2 = (const float*)d_in[11]; const float* cb2 = (const float*)d_in[12];
    const float* cw3 = (const float*)d_in[13]; const float* cb3 = (const float*)d_in[14];
    const float* gw1 = (const float*)d_in[15]; const float* gb1 = (const float*)d_in[16];
    const float* gw2 = (const float*)d_in[17]; const float* gb2 = (const float*)d_in[18];
    const float* wd1 = (const float*)d_in[19]; const float* bd1 = (const float*)d_in[20];
    const float* wc1 = (const float*)d_in[21]; const float* bc1 = (const float*)d_in[22];
    const float* wd2 = (const float*)d_in[23]; const float* bd2 = (const float*)d_in[24];
    const float* wc2 = (const float*)d_in[25]; const float* bc2 = (const float*)d_in[26];

    char* p = (char*)d_ws;
    auto alloc = [&](size_t bytes)->char* {
        char* r = p;
        p += (bytes + 255) & ~(size_t)255;
        return r;
    };
    u16* gbf = (u16*)alloc((size_t)NLP*EP*2);
    u16* h1  = (u16*)alloc((size_t)NLP*EP*2);
    u16* agg = (u16*)alloc((size_t)NLP*EP*2);
    u16* lfb = (u16*)alloc((size_t)NLP*EP*2);
    u16* xA  = (u16*)alloc((size_t)MROWS*EP*2);
    u16* xB  = (u16*)alloc((size_t)MROWS*EP*2);
    u16* wcv1 = (u16*)alloc((size_t)768*EP*2);
    u16* wcv2 = (u16*)alloc((size_t)768*EP*2);
    u16* wcv3 = (u16*)alloc((size_t)768*EP*2);
    u16* wdn1 = (u16*)alloc((size_t)256*EP*2);
    u16* wdn2 = (u16*)alloc((size_t)256*EP*2);
    float* xf = (float*)alloc((size_t)4*NLP*4);
    float* zt = (float*)alloc((size_t)NLP*4*4);       // transposed sigmoid [n][4]
    float* pcb = (float*)alloc((size_t)2*CORN*4*4);   // cord partials [2][CORN][4]
    int* deg  = (int*)alloc((size_t)NLP*4);
    int* part = (int*)alloc((size_t)128*4);
    int* rp   = (int*)alloc((size_t)(NLP+1)*4);
    int* cur  = (int*)alloc((size_t)NLP*4);
    int* esrc = (int*)alloc((size_t)NEDGE*4);

    hipMemsetAsync(deg, 0, (size_t)NLP*4, stream);

    // fused prep + degree count
    PrepArgs pa{ g, gbf, gw1, wdn1, gw2, wdn2, cw1, wcv1, cw2, wcv2, cw3, wcv3,
                 t0, t1, t2, t3, t4, emb, xA };
    k_prep_all<<<PREP_TOT + 1776, 256, 0, stream>>>(pa, dst, deg);

    // CSR build: parallel 2-kernel scan, then scatter
    k_scan1<<<111, 256, 0, stream>>>(deg, part);
    k_scan23<<<111, 256, 0, stream>>>(deg, part, rp, cur);
    k_scatter<<<1776, 256, 0, stream>>>(src, dst, cur, esrc);

    const int SM_D = (2*64*40 + 2*64*40)*2;    // 20480

    // LabelNet + conv chain, independent paths overlapped in dual launches
    k_agg<<<(NL+7)/8, 256, 0, stream>>>(gbf, rp, esrc, agg);
    k_gemm_dual<1,64,64, 0,64,64><<<1776+320, 256, SM_D, stream>>>(
        1776, 4, 4,
        agg, wdn1, h1, gb1, nullptr, 0,
        xA,  wcv1, xB, cb1, nullptr, 1);
    k_agg<<<(NL+7)/8, 256, 0, stream>>>(h1, rp, esrc, agg);
    k_gemm_dual<2,64,64, 0,64,64><<<1776+320, 256, SM_D, stream>>>(
        1776, 4, 4,
        agg, wdn2, lfb, gb2, gbf, 0,
        xB,  wcv2, xA,  cb2, nullptr, 2);
    // conv3: write k-major slabs for k_scores
    k_gemm<0,64,64,1><<<dim3(4,80), 256, SM_D, stream>>>(xA, wcv3, xB, cb3, nullptr, 3);

    // fused scores GEMM + softmax-weighted mean + transposed sigmoid
    k_scores<<<dim3(222, 4), 256, 0, stream>>>(xB, lfb, xf, zt);

    // CorNet x2 (split-n cord partials, combine+bias+ELU in corc staging)
    k_cord<<<dim3(CORN, 2), 256, 0, stream>>>((const float4*)zt, wd1, (float4*)pcb);
    k_corc<0><<<1776, 256, 0, stream>>>((const float4*)pcb, bd1, wc1, bc1, xf, (float4*)zt, nullptr);
    k_cord<<<dim3(CORN, 2), 256, 0, stream>>>((const float4*)zt, wd2, (float4*)pcb);
    k_corc<1><<<1776, 256, 0, stream>>>((const float4*)pcb, bd2, wc2, bc2, xf, nullptr, (float*)d_out);
}